// Round 11
// baseline (378.119 us; speedup 1.0000x reference)
//
#include <hip/hip_runtime.h>
#include <math.h>

#define NSUB 128

typedef short bf16x8 __attribute__((ext_vector_type(8)));
typedef float f32x4  __attribute__((ext_vector_type(4)));
typedef unsigned long long u64;

__device__ __forceinline__ unsigned short f2b(float f) {
    unsigned u = __float_as_uint(f);
    unsigned r = (u + 0x7FFFu + ((u >> 16) & 1u)) >> 16;
    return (unsigned short)r;
}
__device__ __forceinline__ float b2f(unsigned short s) {
    return __uint_as_float(((unsigned)s) << 16);
}
__device__ __forceinline__ float gelu_exact(float x) {
    return 0.5f * x * (1.0f + erff(x * 0.70710678118654752f));
}
__device__ __forceinline__ void gload16(const void* g, void* l) {
    __builtin_amdgcn_global_load_lds(
        (const __attribute__((address_space(1))) void*)g,
        (__attribute__((address_space(3))) void*)l, 16, 0, 0);
}

// ---------------------------------------------------------------------------
// bf16 NT MFMA GEMM: C[M,N] = A[M,K] * B[N,K]^T   (A,B bf16 contiguous)
// 128x64 tile, BK=32, 4 waves (2Mx2N), acc 4x2 16x16x32 frags/wave.
// Tile-N halved vs m97 to double grid size (grid was 2 blocks/CU ->
// occupancy 17.7%, MfmaUtil 34%; more blocks/CU = latency hiding).
// SPLIT=1: 3-pass split-precision (Ah*Bh + Ah*Bl + Al*Bh), fp32-class result.
// EPI: 0 store f32; 1 +bias store f32; 2 gelu store bf16; 3 *0.25 store f32.
// ---------------------------------------------------------------------------
template<int EPI, int SPLIT>
__global__ __launch_bounds__(256) void mfma_nt(
    const unsigned short* __restrict__ Ah, const unsigned short* __restrict__ Al,
    const unsigned short* __restrict__ Bh, const unsigned short* __restrict__ Bl,
    int K, float* __restrict__ Cf, unsigned short* __restrict__ Cb, int ldc,
    const float* __restrict__ bias)
{
    constexpr int NT = SPLIT ? 2 : 1;
    __shared__ __align__(16) unsigned short smA[NT][128 * 32];
    __shared__ __align__(16) unsigned short smB[NT][64 * 32];

    const int t = threadIdx.x, w = t >> 6, l = t & 63;
    const size_t arow = (size_t)blockIdx.x * 128;
    const size_t brow = (size_t)blockIdx.y * 64;
    const int srow = l >> 2, scol = (l & 3) * 8;
    const int wr = (w >> 1) * 64, wc = (w & 1) * 32;
    const int fr = l & 15, fc = (l >> 4) * 8;

    f32x4 acc[4][2];
#pragma unroll
    for (int m = 0; m < 4; ++m)
#pragma unroll
        for (int n = 0; n < 2; ++n) acc[m][n] = (f32x4){0.f, 0.f, 0.f, 0.f};

    for (int kt = 0; kt < K; kt += 32) {
        // ---- stage A (128x32) and B (64x32) via global_load_lds ----
#pragma unroll
        for (int i = 0; i < 2; ++i) {
            const int rb = (w * 2 + i) * 16;
            const size_t ga = (arow + rb + srow) * (size_t)K + kt + scol;
            gload16(Ah + ga, &smA[0][rb * 32]);
            if (SPLIT) gload16(Al + ga, &smA[1][rb * 32]);
        }
        {
            const int rb = w * 16;
            const size_t gb = (brow + rb + srow) * (size_t)K + kt + scol;
            gload16(Bh + gb, &smB[0][rb * 32]);
            if (SPLIT) gload16(Bl + gb, &smB[1][rb * 32]);
        }
        __syncthreads();

        bf16x8 fa[4], fb[2];
#pragma unroll
        for (int m = 0; m < 4; ++m)
            fa[m] = *(const bf16x8*)&smA[0][(wr + m * 16 + fr) * 32 + fc];
#pragma unroll
        for (int n = 0; n < 2; ++n)
            fb[n] = *(const bf16x8*)&smB[0][(wc + n * 16 + fr) * 32 + fc];
#pragma unroll
        for (int m = 0; m < 4; ++m)
#pragma unroll
            for (int n = 0; n < 2; ++n)
                acc[m][n] = __builtin_amdgcn_mfma_f32_16x16x32_bf16(
                    fa[m], fb[n], acc[m][n], 0, 0, 0);
        if (SPLIT) {
            bf16x8 la[4], lb[2];
#pragma unroll
            for (int m = 0; m < 4; ++m)
                la[m] = *(const bf16x8*)&smA[1][(wr + m * 16 + fr) * 32 + fc];
#pragma unroll
            for (int n = 0; n < 2; ++n)
                lb[n] = *(const bf16x8*)&smB[1][(wc + n * 16 + fr) * 32 + fc];
#pragma unroll
            for (int m = 0; m < 4; ++m)
#pragma unroll
                for (int n = 0; n < 2; ++n) {
                    acc[m][n] = __builtin_amdgcn_mfma_f32_16x16x32_bf16(
                        fa[m], lb[n], acc[m][n], 0, 0, 0);
                    acc[m][n] = __builtin_amdgcn_mfma_f32_16x16x32_bf16(
                        la[m], fb[n], acc[m][n], 0, 0, 0);
                }
        }
        __syncthreads();
    }

    // ---- epilogue: C/D layout col=l&15, row=(l>>4)*4+j ----
    const int crow = (int)arow + wr + (l >> 4) * 4;
    const int ccol0 = (int)brow + wc + (l & 15);
#pragma unroll
    for (int n = 0; n < 2; ++n) {
        const int col = ccol0 + n * 16;
        float bv = 0.f;
        if (EPI == 1) bv = bias[col];
#pragma unroll
        for (int m = 0; m < 4; ++m)
#pragma unroll
            for (int j = 0; j < 4; ++j) {
                const size_t row = (size_t)(crow + m * 16 + j);
                float v = acc[m][n][j] + ((EPI == 1) ? bv : 0.f);
                if (EPI == 2)      Cb[row * ldc + col] = f2b(gelu_exact(v));
                else if (EPI == 3) Cf[row * ldc + col] = v * 0.25f;
                else               Cf[row * ldc + col] = v;
            }
    }
}

// ---------------------------------------------------------------------------
// fp32 GEMM for the selection score matmul:
// S[n][hp*128+k] = (q[:, hp-window]*scale+shift) @ sk_p^T, K=128
// ---------------------------------------------------------------------------
__global__ __launch_bounds__(256) void gemm_shead(
    const float* __restrict__ A, int lda,
    const float* __restrict__ B0, const float* __restrict__ B1, int ldb,
    float* __restrict__ C, int ldc, int K,
    const float* __restrict__ aux0, const float* __restrict__ aux1)
{
    __shared__ float sa[16][128];
    __shared__ float sb[16][132];

    const int t = threadIdx.x;
    const int bm = blockIdx.x;
    const int hp = blockIdx.y;
    const int acoff = (hp >> 1) * 256 + (hp & 1) * 128;
    const int ccoff = hp * 128;
    const float* B = (hp & 1) ? B1 : B0;

    const int r = t >> 1, kh = t & 1;
    const int tx = t & 15, ty = t >> 4;
    float acc[8][8] = {};

    const float* Arow = A + (size_t)(bm * 128 + r) * lda + acoff + kh * 8;

    for (int kt = 0; kt < K; kt += 16) {
        float a[8];
        *(float4*)&a[0] = *(const float4*)(Arow + kt);
        *(float4*)&a[4] = *(const float4*)(Arow + kt + 4);
        const int ch = acoff + kt + kh * 8;
        float sc[8], sh[8];
        *(float4*)&sc[0] = *(const float4*)(aux0 + ch);
        *(float4*)&sc[4] = *(const float4*)(aux0 + ch + 4);
        *(float4*)&sh[0] = *(const float4*)(aux1 + ch);
        *(float4*)&sh[4] = *(const float4*)(aux1 + ch + 4);
#pragma unroll
        for (int i = 0; i < 8; ++i) a[i] = fmaf(a[i], sc[i], sh[i]);
#pragma unroll
        for (int i = 0; i < 8; ++i) sa[kh * 8 + i][r] = a[i];

        const float* Brow = B + (size_t)r * ldb + kh * 8 + kt;
        float b[8];
        *(float4*)&b[0] = *(const float4*)(Brow);
        *(float4*)&b[4] = *(const float4*)(Brow + 4);
#pragma unroll
        for (int i = 0; i < 8; ++i) sb[kh * 8 + i][r] = b[i];
        __syncthreads();

#pragma unroll
        for (int k = 0; k < 16; ++k) {
            float av[8], bv[8];
            *(float4*)&av[0] = *(const float4*)&sa[k][ty * 8];
            *(float4*)&av[4] = *(const float4*)&sa[k][ty * 8 + 4];
            *(float4*)&bv[0] = *(const float4*)&sb[k][tx * 8];
            *(float4*)&bv[4] = *(const float4*)&sb[k][tx * 8 + 4];
#pragma unroll
            for (int i = 0; i < 8; ++i)
#pragma unroll
                for (int j = 0; j < 8; ++j)
                    acc[i][j] = fmaf(av[i], bv[j], acc[i][j]);
        }
        __syncthreads();
    }
#pragma unroll
    for (int i = 0; i < 8; ++i) {
        const size_t row = (size_t)(bm * 128) + ty * 8 + i;
#pragma unroll
        for (int jv = 0; jv < 2; ++jv) {
            const int col = tx * 8 + jv * 4;
            *(float4*)(C + row * (size_t)ldc + ccoff + col) = *(float4*)&acc[i][jv * 4];
        }
    }
}

// ---------------------------------------------------------------------------
// Merged prep: split x, split Wq, cast W2a, transpose-cast W1t and Wvt.
// ---------------------------------------------------------------------------
__global__ __launch_bounds__(256) void prep_all(
    const float* __restrict__ x, const float* __restrict__ Wq,
    const float* __restrict__ W2, const float* __restrict__ W1,
    unsigned short* __restrict__ xh, unsigned short* __restrict__ xl,
    unsigned short* __restrict__ Wqh, unsigned short* __restrict__ Wql,
    unsigned short* __restrict__ W2a, unsigned short* __restrict__ W1t,
    unsigned short* __restrict__ Wvt)
{
    const int idx = blockIdx.x * 256 + threadIdx.x;
    if (idx < 2097152) {                     // split x (float4)
        float4 v = *(const float4*)&x[(size_t)idx * 4];
        ushort4 h, l;
        h.x = f2b(v.x); l.x = f2b(v.x - b2f(h.x));
        h.y = f2b(v.y); l.y = f2b(v.y - b2f(h.y));
        h.z = f2b(v.z); l.z = f2b(v.z - b2f(h.z));
        h.w = f2b(v.w); l.w = f2b(v.w - b2f(h.w));
        *(ushort4*)&xh[(size_t)idx * 4] = h;
        *(ushort4*)&xl[(size_t)idx * 4] = l;
    } else if (idx < 2359296) {              // split Wq (float4)
        const int j = idx - 2097152;
        float4 v = *(const float4*)&Wq[(size_t)j * 4];
        ushort4 h, l;
        h.x = f2b(v.x); l.x = f2b(v.x - b2f(h.x));
        h.y = f2b(v.y); l.y = f2b(v.y - b2f(h.y));
        h.z = f2b(v.z); l.z = f2b(v.z - b2f(h.z));
        h.w = f2b(v.w); l.w = f2b(v.w - b2f(h.w));
        *(ushort4*)&Wqh[(size_t)j * 4] = h;
        *(ushort4*)&Wql[(size_t)j * 4] = l;
    } else if (idx < 2490368) {              // W2a[f][d] = W2[f][d] (float4)
        const int j = idx - 2359296;
        const int r = j >> 8, c4 = (j & 255) * 4;
        float4 v = *(const float4*)&W2[(size_t)r * 2048 + c4];
        ushort4 o;
        o.x = f2b(v.x); o.y = f2b(v.y); o.z = f2b(v.z); o.w = f2b(v.w);
        *(ushort4*)&W2a[(size_t)r * 1024 + c4] = o;
    } else if (idx < 2621440) {              // W1t[f][d] = W1[d][f] (scalar)
        const int j = idx - 2490368;
        const int r = j >> 8, c = j & 255;
        W1t[j] = f2b(W1[(size_t)c * 512 + r]);
    } else if (idx < 3145728) {              // Wvt[d][f] = W2[f][1024+d]
        const int j = idx - 2621440;
        const int r = j >> 9, c = j & 511;
        Wvt[j] = f2b(W2[(size_t)c * 2048 + 1024 + r]);
    }
}

__global__ __launch_bounds__(256) void cast_rows(
    const float* __restrict__ src, int srld, unsigned short* __restrict__ dst,
    int rows, int cols)
{
    const int idx = blockIdx.x * 256 + threadIdx.x;
    const int tot = rows * (cols >> 2);
    if (idx >= tot) return;
    const int r = idx / (cols >> 2), c4 = (idx % (cols >> 2)) * 4;
    float4 v = *(const float4*)&src[(size_t)r * srld + c4];
    ushort4 o;
    o.x = f2b(v.x); o.y = f2b(v.y); o.z = f2b(v.z); o.w = f2b(v.w);
    *(ushort4*)&dst[(size_t)r * cols + c4] = o;
}

// ---------------------------------------------------------------------------
// BatchNorm statistics over rows of q[8192][1024]
// ---------------------------------------------------------------------------
__global__ __launch_bounds__(256) void col_stats_partial(
    const float* __restrict__ q, float* __restrict__ ps, float* __restrict__ pq)
{
    const int b = blockIdx.x;
    const int t = threadIdx.x;
    float4 s = make_float4(0.f, 0.f, 0.f, 0.f);
    float4 sq = make_float4(0.f, 0.f, 0.f, 0.f);
    const float* base = q + (size_t)b * 32 * 1024 + t * 4;
#pragma unroll 4
    for (int r = 0; r < 32; ++r) {
        float4 v = *(const float4*)(base + (size_t)r * 1024);
        s.x += v.x; s.y += v.y; s.z += v.z; s.w += v.w;
        sq.x = fmaf(v.x, v.x, sq.x); sq.y = fmaf(v.y, v.y, sq.y);
        sq.z = fmaf(v.z, v.z, sq.z); sq.w = fmaf(v.w, v.w, sq.w);
    }
    *(float4*)(ps + b * 1024 + t * 4) = s;
    *(float4*)(pq + b * 1024 + t * 4) = sq;
}

__global__ __launch_bounds__(256) void col_stats_final(
    const float* __restrict__ ps, const float* __restrict__ pq,
    const float* __restrict__ gamma, const float* __restrict__ beta,
    float* __restrict__ scale, float* __restrict__ shift)
{
    const int c = blockIdx.x * 256 + threadIdx.x;
    float s = 0.f, sq = 0.f;
    for (int b = 0; b < 256; ++b) {
        s += ps[b * 1024 + c];
        sq += pq[b * 1024 + c];
    }
    const float mean = s * (1.0f / 8192.0f);
    const float var = sq * (1.0f / 8192.0f) - mean * mean;
    const float g = gamma[c] * rsqrtf(var + 1e-5f);
    scale[c] = g;
    shift[c] = beta[c] - mean * g;
}

// ---------------------------------------------------------------------------
// Selection v4: top-8 bitonic network, DPP/swizzle/bpermute exchanges.
// key = (ord(v) << 7) | (127 - idx): desc sort == (value desc, index asc).
// ---------------------------------------------------------------------------
__device__ __forceinline__ u64 pack_key(float v, int idx) {
    unsigned u = __float_as_uint(v);
    unsigned ord = (u & 0x80000000u) ? ~u : (u | 0x80000000u);
    return ((u64)ord << 7) | (unsigned)(127 - idx);
}
__device__ __forceinline__ float key_val(u64 k) {
    unsigned ord = (unsigned)(k >> 7);
    unsigned u = (ord & 0x80000000u) ? (ord ^ 0x80000000u) : ~ord;
    return __uint_as_float(u);
}
__device__ __forceinline__ int key_idx(u64 k) {
    return 127 - (int)(k & 127u);
}
template<int CTRL>
__device__ __forceinline__ u64 dpp64(u64 v) {
    unsigned lo = (unsigned)__builtin_amdgcn_update_dpp(
        0, (int)(unsigned)v, CTRL, 0xF, 0xF, true);
    unsigned hi = (unsigned)__builtin_amdgcn_update_dpp(
        0, (int)(unsigned)(v >> 32), CTRL, 0xF, 0xF, true);
    return ((u64)hi << 32) | lo;
}
template<int IMM>
__device__ __forceinline__ u64 swz64(u64 v) {
    unsigned lo = (unsigned)__builtin_amdgcn_ds_swizzle((int)(unsigned)v, IMM);
    unsigned hi = (unsigned)__builtin_amdgcn_ds_swizzle((int)(unsigned)(v >> 32), IMM);
    return ((u64)hi << 32) | lo;
}
__device__ __forceinline__ u64 sx64(u64 v, int m) {
    unsigned lo = __shfl_xor((unsigned)v, m);
    unsigned hi = __shfl_xor((unsigned)(v >> 32), m);
    return ((u64)hi << 32) | lo;
}
__device__ __forceinline__ u64 sg64(u64 v, int src) {
    unsigned lo = __shfl((unsigned)v, src);
    unsigned hi = __shfl((unsigned)(v >> 32), src);
    return ((u64)hi << 32) | lo;
}
#define XK(k, p, kp) k = (((k) > (p)) == (kp)) ? (k) : (p)
template<int CTRL>
__device__ __forceinline__ void cx4d(u64& a0, u64& a1, u64& b0, u64& b1, bool kp) {
    u64 p;
    p = dpp64<CTRL>(a0); XK(a0, p, kp);
    p = dpp64<CTRL>(a1); XK(a1, p, kp);
    p = dpp64<CTRL>(b0); XK(b0, p, kp);
    p = dpp64<CTRL>(b1); XK(b1, p, kp);
}
template<int IMM>
__device__ __forceinline__ void cx4s(u64& a0, u64& a1, u64& b0, u64& b1, bool kp) {
    u64 p;
    p = swz64<IMM>(a0); XK(a0, p, kp);
    p = swz64<IMM>(a1); XK(a1, p, kp);
    p = swz64<IMM>(b0); XK(b0, p, kp);
    p = swz64<IMM>(b1); XK(b1, p, kp);
}
__device__ __forceinline__ void cx4b(u64& a0, u64& a1, u64& b0, u64& b1,
                                     int m, bool kp) {
    u64 p;
    p = sx64(a0, m); XK(a0, p, kp);
    p = sx64(a1, m); XK(a1, p, kp);
    p = sx64(b0, m); XK(b0, p, kp);
    p = sx64(b1, m); XK(b1, p, kp);
}
template<int CTRL>
__device__ __forceinline__ void cx2d(u64& a0, u64& b0, bool kp) {
    u64 p;
    p = dpp64<CTRL>(a0); XK(a0, p, kp);
    p = dpp64<CTRL>(b0); XK(b0, p, kp);
}
template<int IMM>
__device__ __forceinline__ void cx2s(u64& a0, u64& b0, bool kp) {
    u64 p;
    p = swz64<IMM>(a0); XK(a0, p, kp);
    p = swz64<IMM>(b0); XK(b0, p, kp);
}

#define DPP_X1 0xB1   // quad_perm [1,0,3,2]
#define DPP_X2 0x4E   // quad_perm [2,3,0,1]
#define DPP_X7 0x141  // row_half_mirror
#define DPP_X15 0x140 // row_mirror
#define SWZ_X4  0x101F // BitMode xor=4, and=0x1F
#define SWZ_X23 0x5C1F // BitMode xor=23, and=0x1F

__global__ __launch_bounds__(256) void select_topk(
    const float* __restrict__ S, int* __restrict__ Eo, float* __restrict__ Po)
{
    const int lane = threadIdx.x & 63;
    const int pair = blockIdx.x * 4 + (threadIdx.x >> 6);
    const float* s1 = S + (size_t)pair * 256;
    const float* s2 = s1 + 128;

    u64 a0 = pack_key(s1[lane], lane);
    u64 a1 = pack_key(s1[lane + 64], lane + 64);
    u64 b0 = pack_key(s2[lane], lane);
    u64 b1 = pack_key(s2[lane + 64], lane + 64);

    // Phase A: sort every 8-lane block descending (6 stages)
    cx4d<DPP_X1>(a0, a1, b0, b1, ((lane & 1) == 0) == ((lane & 2) == 0));
    cx4d<DPP_X2>(a0, a1, b0, b1, ((lane & 2) == 0) == ((lane & 4) == 0));
    cx4d<DPP_X1>(a0, a1, b0, b1, ((lane & 1) == 0) == ((lane & 4) == 0));
    cx4s<SWZ_X4>(a0, a1, b0, b1, (lane & 4) == 0);
    cx4d<DPP_X2>(a0, a1, b0, b1, (lane & 2) == 0);
    cx4d<DPP_X1>(a0, a1, b0, b1, (lane & 1) == 0);
    // Level 1: merge-prune 8|8 within 16-lane groups (reversal pairing ^15)
    cx4d<DPP_X15>(a0, a1, b0, b1, (lane & 8) == 0);
    cx4s<SWZ_X4>(a0, a1, b0, b1, (lane & 4) == 0);
    cx4d<DPP_X2>(a0, a1, b0, b1, (lane & 2) == 0);
    cx4d<DPP_X1>(a0, a1, b0, b1, (lane & 1) == 0);
    // Level 2: merge lists 16 lanes apart (^23)
    cx4s<SWZ_X23>(a0, a1, b0, b1, (lane & 16) == 0);
    cx4s<SWZ_X4>(a0, a1, b0, b1, (lane & 4) == 0);
    cx4d<DPP_X2>(a0, a1, b0, b1, (lane & 2) == 0);
    cx4d<DPP_X1>(a0, a1, b0, b1, (lane & 1) == 0);
    // Level 3: merge lists 32 lanes apart (^39; crosses 32-lane -> bpermute)
    cx4b(a0, a1, b0, b1, 39, (lane & 32) == 0);
    cx4s<SWZ_X4>(a0, a1, b0, b1, (lane & 4) == 0);
    cx4d<DPP_X2>(a0, a1, b0, b1, (lane & 2) == 0);
    cx4d<DPP_X1>(a0, a1, b0, b1, (lane & 1) == 0);
    // Level C: cross-reg merge (reg1 reversed via ^7), clean on reg0
    {
        u64 p = dpp64<DPP_X7>(a1);
        if (p > a0) a0 = p;
        p = dpp64<DPP_X7>(b1);
        if (p > b0) b0 = p;
    }
    cx2s<SWZ_X4>(a0, b0, (lane & 4) == 0);
    cx2d<DPP_X2>(a0, b0, (lane & 2) == 0);
    cx2d<DPP_X1>(a0, b0, (lane & 1) == 0);
    // now rank-i of s1 at lane i (key a0), same for s2 (key b0), i in [0,8)

    // ---- combo top-8 via dominance pruning: (i+1)*(j+1) <= 8 -> 20 pairs ----
    const int p = lane;
    int ci, cj;
    if (p < 8)       { ci = 0; cj = p; }
    else if (p < 16) { ci = (0x33221111u >> ((p - 8) * 4)) & 15;
                       cj = (0x10103210u >> ((p - 8) * 4)) & 15; }
    else             { ci = p - 12; cj = 0; }

    const u64 k1c = sg64(a0, ci);
    const u64 k2c = sg64(b0, cj);
    const float sum = (p < 20) ? (key_val(k1c) + key_val(k2c)) : -INFINITY;
    const int   c   = ci * 16 + cj;   // flat combo index (tie-break key)

    int rank = 0; float m = -INFINITY;
#pragma unroll
    for (int q = 0; q < 20; ++q) {
        const float sq = __shfl(sum, q);
        const int   cq = __shfl(c, q);
        if (sq > sum || (sq == sum && cq < c)) ++rank;
        m = fmaxf(m, sq);
    }

    float ex = (p < 20 && rank < 8) ? expf(sum - m) : 0.f;
    float esum = ex;
#pragma unroll
    for (int off = 1; off < 64; off <<= 1) esum += __shfl_xor(esum, off);

    if (p < 20 && rank < 8) {
        Eo[pair * 8 + rank] = key_idx(k1c) * NSUB + key_idx(k2c);
        Po[pair * 8 + rank] = ex / esum;
    }
}

// ---------------------------------------------------------------------------
// MoE apply v2: all 8 expert-row gathers issued upfront (8x MLP), DPP-only
// wave sum (row_shr 1,2,4,8 + row_bcast 15,31 -> lane 63 -> readlane).
// ---------------------------------------------------------------------------
__device__ __forceinline__ float wave_sum_dpp(float x) {
    float t;
    t = __uint_as_float((unsigned)__builtin_amdgcn_update_dpp(
        0, (int)__float_as_uint(x), 0x111, 0xF, 0xF, true)); x += t; // row_shr:1
    t = __uint_as_float((unsigned)__builtin_amdgcn_update_dpp(
        0, (int)__float_as_uint(x), 0x112, 0xF, 0xF, true)); x += t; // row_shr:2
    t = __uint_as_float((unsigned)__builtin_amdgcn_update_dpp(
        0, (int)__float_as_uint(x), 0x114, 0xF, 0xF, true)); x += t; // row_shr:4
    t = __uint_as_float((unsigned)__builtin_amdgcn_update_dpp(
        0, (int)__float_as_uint(x), 0x118, 0xF, 0xF, true)); x += t; // row_shr:8
    t = __uint_as_float((unsigned)__builtin_amdgcn_update_dpp(
        0, (int)__float_as_uint(x), 0x142, 0xF, 0xF, true)); x += t; // row_bcast:15
    t = __uint_as_float((unsigned)__builtin_amdgcn_update_dpp(
        0, (int)__float_as_uint(x), 0x143, 0xF, 0xF, true)); x += t; // row_bcast:31
    return __uint_as_float((unsigned)__builtin_amdgcn_readlane(
        (int)__float_as_uint(x), 63));
}

__global__ __launch_bounds__(256) void moe_apply(
    const unsigned short* __restrict__ Hall, const float* __restrict__ xproj,
    const int* __restrict__ E, const float* __restrict__ P,
    unsigned short* __restrict__ accb)
{
    const int n = blockIdx.x, t = threadIdx.x, w = t >> 6, lane = t & 63;
    __shared__ float wacc[4][512];

    float xr[8];
    *(float4*)&xr[0] = *(const float4*)&xproj[(size_t)n * 512 + lane * 8];
    *(float4*)&xr[4] = *(const float4*)&xproj[(size_t)n * 512 + lane * 8 + 4];

    const int* Ep = E + ((size_t)n * 4 + w) * 8;
    const float* Pp = P + ((size_t)n * 4 + w) * 8;

    // wave-uniform expert ids -> SGPR; issue all 8 gathers before any compute
    int e[8]; float pp[8];
#pragma unroll
    for (int k = 0; k < 8; ++k) {
        e[k] = __builtin_amdgcn_readfirstlane(Ep[k]);
        pp[k] = Pp[k];
    }
    bf16x8 hv[8];
#pragma unroll
    for (int k = 0; k < 8; ++k)
        hv[k] = *(const bf16x8*)&Hall[(size_t)e[k] * 512 + lane * 8];

    float ar[8] = {};
#pragma unroll
    for (int k = 0; k < 8; ++k) {
        float h[8];
#pragma unroll
        for (int j = 0; j < 8; ++j) h[j] = b2f((unsigned short)hv[k][j]);
        float d = 0.f;
#pragma unroll
        for (int j = 0; j < 8; ++j) d = fmaf(h[j], xr[j], d);
        d = wave_sum_dpp(d);
        const float act = gelu_exact(d) * pp[k];
#pragma unroll
        for (int j = 0; j < 8; ++j) ar[j] = fmaf(act, h[j], ar[j]);
    }
    *(float4*)&wacc[w][lane * 8] = *(float4*)&ar[0];
    *(float4*)&wacc[w][lane * 8 + 4] = *(float4*)&ar[4];
    __syncthreads();

    const float r0 = wacc[0][t] + wacc[1][t] + wacc[2][t] + wacc[3][t];
    const float r1 = wacc[0][t + 256] + wacc[1][t + 256] + wacc[2][t + 256] + wacc[3][t + 256];
    accb[(size_t)n * 512 + t] = f2b(r0);
    accb[(size_t)n * 512 + 256 + t] = f2b(r1);
}

// ---------------------------------------------------------------------------
extern "C" void kernel_launch(void* const* d_in, const int* in_sizes, int n_in,
                              void* d_out, int out_size, void* d_ws, size_t ws_size,
                              hipStream_t stream)
{
    const float* x       = (const float*)d_in[0];
    const float* Wq      = (const float*)d_in[1];
    const float* bq      = (const float*)d_in[2];
    const float* gamma   = (const float*)d_in[3];
    const float* beta    = (const float*)d_in[4];
    const float* sk1     = (const float*)d_in[5];
    const float* sk2     = (const float*)d_in[6];
    const float* latents = (const float*)d_in[7];
    const float* W1      = (const float*)d_in[8];
    const float* W2      = (const float*)d_in[9];
    float* out = (float*)d_out;
    float* ws  = (float*)d_ws;

    // workspace layout (float offsets), peak 22087680 floats = 88.35 MB.
    // Stream-order-safe aliases (write-before-read checked per launch order):
    //   q [0,8.4M) ............ written s1, read s2/s3; -> Hall bf16 (s5+)
    //   xh [8.4M,12.6M) ........ written s0, read s1,s6; -> S (s3)
    //   xl [12.6M,16.8M) ....... written s0, read s1; -> ps/pq (s2) -> S (s3)
    //   S  [8.4M,16.8M) ........ written s3, read s4; -> accb (s7), latb (after s4)
    //   Wqh/Wql in xproj region: read s1; xproj written s6 (after s1)
    float*          q     = ws;
    unsigned short* Hall  = (unsigned short*)ws;
    unsigned short* xh    = (unsigned short*)(ws + 8388608);
    unsigned short* xl    = (unsigned short*)(ws + 12582912);
    float*          S     = ws + 8388608;
    unsigned short* accb  = (unsigned short*)(ws + 8388608);
    float*          ps    = ws + 12582912;
    float*          pq    = ws + 12845056;
    unsigned short* latb  = (unsigned short*)(ws + 10485760);
    float*          xproj = ws + 16777216;
    unsigned short* Wqh   = (unsigned short*)(ws + 16777216);
    unsigned short* Wql   = (unsigned short*)(ws + 17301504);
    unsigned short* W2a   = (unsigned short*)(ws + 20971520);
    unsigned short* W1t   = (unsigned short*)(ws + 21233664);
    unsigned short* Wvt   = (unsigned short*)(ws + 21299200);
    float*          scale = ws + 21561344;
    float*          shift = ws + 21562368;
    int*            E     = (int*)(ws + 21563392);
    float*          P     = ws + 21825536;

    // 0. merged casts/splits (latents cast deferred until S region is dead)
    prep_all<<<12288, 256, 0, stream>>>(x, Wq, W2, W1,
                                        xh, xl, Wqh, Wql, W2a, W1t, Wvt);

    // 1. q = x @ Wq^T + bq   (split-precision MFMA, fp32-class accuracy)
    mfma_nt<1, 1><<<dim3(64, 16), 256, 0, stream>>>(
        xh, xl, Wqh, Wql, 1024, q, nullptr, 1024, bq);

    // 2. batchnorm stats
    col_stats_partial<<<256, 256, 0, stream>>>(q, ps, pq);
    col_stats_final<<<4, 256, 0, stream>>>(ps, pq, gamma, beta, scale, shift);

    // 6. x_proj = x @ W2[:, :1024]^T  (bf16 MFMA; before S overwrites xh;
    //    destroys Wqh/Wql which are now dead)
    mfma_nt<0, 0><<<dim3(64, 8), 256, 0, stream>>>(
        xh, nullptr, W2a, nullptr, 1024, xproj, nullptr, 512, nullptr);

    // 3. S = (q*scale+shift) @ sk^T   (fp32 for selection exactness)
    gemm_shead<<<dim3(64, 8), 256, 0, stream>>>(
        q, 1024, sk1, sk2, 128, S, 1024, 128, scale, shift);

    // 4. top-k selection (DPP/swizzle bitonic + dominance-pruned combos)
    select_topk<<<8192, 256, 0, stream>>>(S, E, P);

    // 0b. latents cast (into dead S region)
    cast_rows<<<4096, 256, 0, stream>>>(latents, 256, latb, 16384, 256);

    // 5. H_all = gelu(latents @ W1) -> bf16   [overwrites q]
    mfma_nt<2, 0><<<dim3(128, 8), 256, 0, stream>>>(
        latb, nullptr, W1t, nullptr, 256, nullptr, Hall, 512, nullptr);

    // 7. gather + gate + weighted accumulate -> accb bf16  [overwrites S head]
    moe_apply<<<8192, 256, 0, stream>>>(Hall, xproj, E, P, accb);

    // 8. out = acc @ Wv / 4
    mfma_nt<3, 0><<<dim3(64, 16), 256, 0, stream>>>(
        accb, nullptr, Wvt, nullptr, 512, out, nullptr, 1024, nullptr);
}

// Round 12
// 361.297 us; speedup vs baseline: 1.0466x; 1.0466x over previous
//
#include <hip/hip_runtime.h>
#include <math.h>

#define NSUB 128

typedef short bf16x8 __attribute__((ext_vector_type(8)));
typedef float f32x4  __attribute__((ext_vector_type(4)));
typedef unsigned long long u64;

__device__ __forceinline__ unsigned short f2b(float f) {
    unsigned u = __float_as_uint(f);
    unsigned r = (u + 0x7FFFu + ((u >> 16) & 1u)) >> 16;
    return (unsigned short)r;
}
__device__ __forceinline__ float b2f(unsigned short s) {
    return __uint_as_float(((unsigned)s) << 16);
}
__device__ __forceinline__ float gelu_exact(float x) {
    return 0.5f * x * (1.0f + erff(x * 0.70710678118654752f));
}
__device__ __forceinline__ void gload16(const void* g, void* l) {
    __builtin_amdgcn_global_load_lds(
        (const __attribute__((address_space(1))) void*)g,
        (__attribute__((address_space(3))) void*)l, 16, 0, 0);
}

// ---------------------------------------------------------------------------
// bf16 NT MFMA GEMM: C[M,N] = A[M,K] * B[N,K]^T   (A,B bf16 contiguous)
// 128x128 tile (measured best; r11's 128x64 regressed: less MFMA/barrier),
// BK=64 in two 32-col SUB-PLANES [2][128][32] (row stride stays 64B ->
// same 8-way conflict as BK=32, but barrier count halves -> amortizes the
// vmcnt(0)+barrier drain that caps the m97 structure).
// 4 waves (2x2), 4x4 16x16x32 frags/wave. Bit-identical accumulation order.
// SPLIT=1: 3-pass split-precision (Ah*Bh + Ah*Bl + Al*Bh), fp32-class result.
// EPI: 0 store f32; 1 +bias store f32; 2 gelu store bf16; 3 *0.25 store f32.
// ---------------------------------------------------------------------------
template<int EPI, int SPLIT>
__global__ __launch_bounds__(256) void mfma_nt(
    const unsigned short* __restrict__ Ah, const unsigned short* __restrict__ Al,
    const unsigned short* __restrict__ Bh, const unsigned short* __restrict__ Bl,
    int K, float* __restrict__ Cf, unsigned short* __restrict__ Cb, int ldc,
    const float* __restrict__ bias)
{
    constexpr int NT = SPLIT ? 4 : 2;   // planes: Ah,Bh[,Al,Bl]
    __shared__ __align__(16) unsigned short smem[NT][2][128 * 32];

    const int t = threadIdx.x, w = t >> 6, l = t & 63;
    const size_t arow = (size_t)blockIdx.x * 128;
    const size_t brow = (size_t)blockIdx.y * 128;
    const int srow = l >> 2, scol = (l & 3) * 8;     // 16 rows x 32 cols/gload
    const int wr = (w >> 1) * 64, wc = (w & 1) * 64;
    const int fr = l & 15, fc = (l >> 4) * 8;

    f32x4 acc[4][4];
#pragma unroll
    for (int m = 0; m < 4; ++m)
#pragma unroll
        for (int n = 0; n < 4; ++n) acc[m][n] = (f32x4){0.f, 0.f, 0.f, 0.f};

    for (int kt = 0; kt < K; kt += 64) {
        // ---- stage: per wave 32 rows; 2 sub-planes x 2 row-groups ----
#pragma unroll
        for (int g = 0; g < 2; ++g) {
            const int rb = w * 32 + g * 16;
#pragma unroll
            for (int ks = 0; ks < 2; ++ks) {
                const size_t ga = (arow + rb + srow) * (size_t)K + kt + ks * 32 + scol;
                const size_t gb = (brow + rb + srow) * (size_t)K + kt + ks * 32 + scol;
                gload16(Ah + ga, &smem[0][ks][rb * 32]);
                gload16(Bh + gb, &smem[1][ks][rb * 32]);
                if (SPLIT) {
                    gload16(Al + ga, &smem[2][ks][rb * 32]);
                    gload16(Bl + gb, &smem[3][ks][rb * 32]);
                }
            }
        }
        __syncthreads();

#pragma unroll
        for (int ks = 0; ks < 2; ++ks) {
            bf16x8 fa[4], fb[4];
#pragma unroll
            for (int m = 0; m < 4; ++m)
                fa[m] = *(const bf16x8*)&smem[0][ks][(wr + m * 16 + fr) * 32 + fc];
#pragma unroll
            for (int n = 0; n < 4; ++n)
                fb[n] = *(const bf16x8*)&smem[1][ks][(wc + n * 16 + fr) * 32 + fc];
#pragma unroll
            for (int m = 0; m < 4; ++m)
#pragma unroll
                for (int n = 0; n < 4; ++n)
                    acc[m][n] = __builtin_amdgcn_mfma_f32_16x16x32_bf16(
                        fa[m], fb[n], acc[m][n], 0, 0, 0);
            if (SPLIT) {
                bf16x8 la[4], lb[4];
#pragma unroll
                for (int m = 0; m < 4; ++m)
                    la[m] = *(const bf16x8*)&smem[2][ks][(wr + m * 16 + fr) * 32 + fc];
#pragma unroll
                for (int n = 0; n < 4; ++n)
                    lb[n] = *(const bf16x8*)&smem[3][ks][(wc + n * 16 + fr) * 32 + fc];
#pragma unroll
                for (int m = 0; m < 4; ++m)
#pragma unroll
                    for (int n = 0; n < 4; ++n) {
                        acc[m][n] = __builtin_amdgcn_mfma_f32_16x16x32_bf16(
                            fa[m], lb[n], acc[m][n], 0, 0, 0);
                        acc[m][n] = __builtin_amdgcn_mfma_f32_16x16x32_bf16(
                            la[m], fb[n], acc[m][n], 0, 0, 0);
                    }
            }
        }
        __syncthreads();
    }

    // ---- epilogue: C/D layout col=l&15, row=(l>>4)*4+j ----
    const int crow = (int)arow + wr + (l >> 4) * 4;
    const int ccol0 = (int)brow + wc + (l & 15);
#pragma unroll
    for (int n = 0; n < 4; ++n) {
        const int col = ccol0 + n * 16;
        float bv = 0.f;
        if (EPI == 1) bv = bias[col];
#pragma unroll
        for (int m = 0; m < 4; ++m)
#pragma unroll
            for (int j = 0; j < 4; ++j) {
                const size_t row = (size_t)(crow + m * 16 + j);
                float v = acc[m][n][j] + ((EPI == 1) ? bv : 0.f);
                if (EPI == 2)      Cb[row * ldc + col] = f2b(gelu_exact(v));
                else if (EPI == 3) Cf[row * ldc + col] = v * 0.25f;
                else               Cf[row * ldc + col] = v;
            }
    }
}

// ---------------------------------------------------------------------------
// fp32 GEMM for the selection score matmul:
// S[n][hp*128+k] = (q[:, hp-window]*scale+shift) @ sk_p^T, K=128
// ---------------------------------------------------------------------------
__global__ __launch_bounds__(256) void gemm_shead(
    const float* __restrict__ A, int lda,
    const float* __restrict__ B0, const float* __restrict__ B1, int ldb,
    float* __restrict__ C, int ldc, int K,
    const float* __restrict__ aux0, const float* __restrict__ aux1)
{
    __shared__ float sa[16][128];
    __shared__ float sb[16][132];

    const int t = threadIdx.x;
    const int bm = blockIdx.x;
    const int hp = blockIdx.y;
    const int acoff = (hp >> 1) * 256 + (hp & 1) * 128;
    const int ccoff = hp * 128;
    const float* B = (hp & 1) ? B1 : B0;

    const int r = t >> 1, kh = t & 1;
    const int tx = t & 15, ty = t >> 4;
    float acc[8][8] = {};

    const float* Arow = A + (size_t)(bm * 128 + r) * lda + acoff + kh * 8;

    for (int kt = 0; kt < K; kt += 16) {
        float a[8];
        *(float4*)&a[0] = *(const float4*)(Arow + kt);
        *(float4*)&a[4] = *(const float4*)(Arow + kt + 4);
        const int ch = acoff + kt + kh * 8;
        float sc[8], sh[8];
        *(float4*)&sc[0] = *(const float4*)(aux0 + ch);
        *(float4*)&sc[4] = *(const float4*)(aux0 + ch + 4);
        *(float4*)&sh[0] = *(const float4*)(aux1 + ch);
        *(float4*)&sh[4] = *(const float4*)(aux1 + ch + 4);
#pragma unroll
        for (int i = 0; i < 8; ++i) a[i] = fmaf(a[i], sc[i], sh[i]);
#pragma unroll
        for (int i = 0; i < 8; ++i) sa[kh * 8 + i][r] = a[i];

        const float* Brow = B + (size_t)r * ldb + kh * 8 + kt;
        float b[8];
        *(float4*)&b[0] = *(const float4*)(Brow);
        *(float4*)&b[4] = *(const float4*)(Brow + 4);
#pragma unroll
        for (int i = 0; i < 8; ++i) sb[kh * 8 + i][r] = b[i];
        __syncthreads();

#pragma unroll
        for (int k = 0; k < 16; ++k) {
            float av[8], bv[8];
            *(float4*)&av[0] = *(const float4*)&sa[k][ty * 8];
            *(float4*)&av[4] = *(const float4*)&sa[k][ty * 8 + 4];
            *(float4*)&bv[0] = *(const float4*)&sb[k][tx * 8];
            *(float4*)&bv[4] = *(const float4*)&sb[k][tx * 8 + 4];
#pragma unroll
            for (int i = 0; i < 8; ++i)
#pragma unroll
                for (int j = 0; j < 8; ++j)
                    acc[i][j] = fmaf(av[i], bv[j], acc[i][j]);
        }
        __syncthreads();
    }
#pragma unroll
    for (int i = 0; i < 8; ++i) {
        const size_t row = (size_t)(bm * 128) + ty * 8 + i;
#pragma unroll
        for (int jv = 0; jv < 2; ++jv) {
            const int col = tx * 8 + jv * 4;
            *(float4*)(C + row * (size_t)ldc + ccoff + col) = *(float4*)&acc[i][jv * 4];
        }
    }
}

// ---------------------------------------------------------------------------
// Merged prep: split x, split Wq, cast W2a, transpose-cast W1t and Wvt.
// ---------------------------------------------------------------------------
__global__ __launch_bounds__(256) void prep_all(
    const float* __restrict__ x, const float* __restrict__ Wq,
    const float* __restrict__ W2, const float* __restrict__ W1,
    unsigned short* __restrict__ xh, unsigned short* __restrict__ xl,
    unsigned short* __restrict__ Wqh, unsigned short* __restrict__ Wql,
    unsigned short* __restrict__ W2a, unsigned short* __restrict__ W1t,
    unsigned short* __restrict__ Wvt)
{
    const int idx = blockIdx.x * 256 + threadIdx.x;
    if (idx < 2097152) {                     // split x (float4)
        float4 v = *(const float4*)&x[(size_t)idx * 4];
        ushort4 h, l;
        h.x = f2b(v.x); l.x = f2b(v.x - b2f(h.x));
        h.y = f2b(v.y); l.y = f2b(v.y - b2f(h.y));
        h.z = f2b(v.z); l.z = f2b(v.z - b2f(h.z));
        h.w = f2b(v.w); l.w = f2b(v.w - b2f(h.w));
        *(ushort4*)&xh[(size_t)idx * 4] = h;
        *(ushort4*)&xl[(size_t)idx * 4] = l;
    } else if (idx < 2359296) {              // split Wq (float4)
        const int j = idx - 2097152;
        float4 v = *(const float4*)&Wq[(size_t)j * 4];
        ushort4 h, l;
        h.x = f2b(v.x); l.x = f2b(v.x - b2f(h.x));
        h.y = f2b(v.y); l.y = f2b(v.y - b2f(h.y));
        h.z = f2b(v.z); l.z = f2b(v.z - b2f(h.z));
        h.w = f2b(v.w); l.w = f2b(v.w - b2f(h.w));
        *(ushort4*)&Wqh[(size_t)j * 4] = h;
        *(ushort4*)&Wql[(size_t)j * 4] = l;
    } else if (idx < 2490368) {              // W2a[f][d] = W2[f][d] (float4)
        const int j = idx - 2359296;
        const int r = j >> 8, c4 = (j & 255) * 4;
        float4 v = *(const float4*)&W2[(size_t)r * 2048 + c4];
        ushort4 o;
        o.x = f2b(v.x); o.y = f2b(v.y); o.z = f2b(v.z); o.w = f2b(v.w);
        *(ushort4*)&W2a[(size_t)r * 1024 + c4] = o;
    } else if (idx < 2621440) {              // W1t[f][d] = W1[d][f] (scalar)
        const int j = idx - 2490368;
        const int r = j >> 8, c = j & 255;
        W1t[j] = f2b(W1[(size_t)c * 512 + r]);
    } else if (idx < 3145728) {              // Wvt[d][f] = W2[f][1024+d]
        const int j = idx - 2621440;
        const int r = j >> 9, c = j & 511;
        Wvt[j] = f2b(W2[(size_t)c * 2048 + 1024 + r]);
    }
}

__global__ __launch_bounds__(256) void cast_rows(
    const float* __restrict__ src, int srld, unsigned short* __restrict__ dst,
    int rows, int cols)
{
    const int idx = blockIdx.x * 256 + threadIdx.x;
    const int tot = rows * (cols >> 2);
    if (idx >= tot) return;
    const int r = idx / (cols >> 2), c4 = (idx % (cols >> 2)) * 4;
    float4 v = *(const float4*)&src[(size_t)r * srld + c4];
    ushort4 o;
    o.x = f2b(v.x); o.y = f2b(v.y); o.z = f2b(v.z); o.w = f2b(v.w);
    *(ushort4*)&dst[(size_t)r * cols + c4] = o;
}

// ---------------------------------------------------------------------------
// BatchNorm statistics over rows of q[8192][1024]
// ---------------------------------------------------------------------------
__global__ __launch_bounds__(256) void col_stats_partial(
    const float* __restrict__ q, float* __restrict__ ps, float* __restrict__ pq)
{
    const int b = blockIdx.x;
    const int t = threadIdx.x;
    float4 s = make_float4(0.f, 0.f, 0.f, 0.f);
    float4 sq = make_float4(0.f, 0.f, 0.f, 0.f);
    const float* base = q + (size_t)b * 32 * 1024 + t * 4;
#pragma unroll 4
    for (int r = 0; r < 32; ++r) {
        float4 v = *(const float4*)(base + (size_t)r * 1024);
        s.x += v.x; s.y += v.y; s.z += v.z; s.w += v.w;
        sq.x = fmaf(v.x, v.x, sq.x); sq.y = fmaf(v.y, v.y, sq.y);
        sq.z = fmaf(v.z, v.z, sq.z); sq.w = fmaf(v.w, v.w, sq.w);
    }
    *(float4*)(ps + b * 1024 + t * 4) = s;
    *(float4*)(pq + b * 1024 + t * 4) = sq;
}

__global__ __launch_bounds__(256) void col_stats_final(
    const float* __restrict__ ps, const float* __restrict__ pq,
    const float* __restrict__ gamma, const float* __restrict__ beta,
    float* __restrict__ scale, float* __restrict__ shift)
{
    const int c = blockIdx.x * 256 + threadIdx.x;
    float s = 0.f, sq = 0.f;
    for (int b = 0; b < 256; ++b) {
        s += ps[b * 1024 + c];
        sq += pq[b * 1024 + c];
    }
    const float mean = s * (1.0f / 8192.0f);
    const float var = sq * (1.0f / 8192.0f) - mean * mean;
    const float g = gamma[c] * rsqrtf(var + 1e-5f);
    scale[c] = g;
    shift[c] = beta[c] - mean * g;
}

// ---------------------------------------------------------------------------
// Selection v4: top-8 bitonic network, DPP/swizzle/bpermute exchanges.
// key = (ord(v) << 7) | (127 - idx): desc sort == (value desc, index asc).
// ---------------------------------------------------------------------------
__device__ __forceinline__ u64 pack_key(float v, int idx) {
    unsigned u = __float_as_uint(v);
    unsigned ord = (u & 0x80000000u) ? ~u : (u | 0x80000000u);
    return ((u64)ord << 7) | (unsigned)(127 - idx);
}
__device__ __forceinline__ float key_val(u64 k) {
    unsigned ord = (unsigned)(k >> 7);
    unsigned u = (ord & 0x80000000u) ? (ord ^ 0x80000000u) : ~ord;
    return __uint_as_float(u);
}
__device__ __forceinline__ int key_idx(u64 k) {
    return 127 - (int)(k & 127u);
}
template<int CTRL>
__device__ __forceinline__ u64 dpp64(u64 v) {
    unsigned lo = (unsigned)__builtin_amdgcn_update_dpp(
        0, (int)(unsigned)v, CTRL, 0xF, 0xF, true);
    unsigned hi = (unsigned)__builtin_amdgcn_update_dpp(
        0, (int)(unsigned)(v >> 32), CTRL, 0xF, 0xF, true);
    return ((u64)hi << 32) | lo;
}
template<int IMM>
__device__ __forceinline__ u64 swz64(u64 v) {
    unsigned lo = (unsigned)__builtin_amdgcn_ds_swizzle((int)(unsigned)v, IMM);
    unsigned hi = (unsigned)__builtin_amdgcn_ds_swizzle((int)(unsigned)(v >> 32), IMM);
    return ((u64)hi << 32) | lo;
}
__device__ __forceinline__ u64 sx64(u64 v, int m) {
    unsigned lo = __shfl_xor((unsigned)v, m);
    unsigned hi = __shfl_xor((unsigned)(v >> 32), m);
    return ((u64)hi << 32) | lo;
}
__device__ __forceinline__ u64 sg64(u64 v, int src) {
    unsigned lo = __shfl((unsigned)v, src);
    unsigned hi = __shfl((unsigned)(v >> 32), src);
    return ((u64)hi << 32) | lo;
}
#define XK(k, p, kp) k = (((k) > (p)) == (kp)) ? (k) : (p)
template<int CTRL>
__device__ __forceinline__ void cx4d(u64& a0, u64& a1, u64& b0, u64& b1, bool kp) {
    u64 p;
    p = dpp64<CTRL>(a0); XK(a0, p, kp);
    p = dpp64<CTRL>(a1); XK(a1, p, kp);
    p = dpp64<CTRL>(b0); XK(b0, p, kp);
    p = dpp64<CTRL>(b1); XK(b1, p, kp);
}
template<int IMM>
__device__ __forceinline__ void cx4s(u64& a0, u64& a1, u64& b0, u64& b1, bool kp) {
    u64 p;
    p = swz64<IMM>(a0); XK(a0, p, kp);
    p = swz64<IMM>(a1); XK(a1, p, kp);
    p = swz64<IMM>(b0); XK(b0, p, kp);
    p = swz64<IMM>(b1); XK(b1, p, kp);
}
__device__ __forceinline__ void cx4b(u64& a0, u64& a1, u64& b0, u64& b1,
                                     int m, bool kp) {
    u64 p;
    p = sx64(a0, m); XK(a0, p, kp);
    p = sx64(a1, m); XK(a1, p, kp);
    p = sx64(b0, m); XK(b0, p, kp);
    p = sx64(b1, m); XK(b1, p, kp);
}
template<int CTRL>
__device__ __forceinline__ void cx2d(u64& a0, u64& b0, bool kp) {
    u64 p;
    p = dpp64<CTRL>(a0); XK(a0, p, kp);
    p = dpp64<CTRL>(b0); XK(b0, p, kp);
}
template<int IMM>
__device__ __forceinline__ void cx2s(u64& a0, u64& b0, bool kp) {
    u64 p;
    p = swz64<IMM>(a0); XK(a0, p, kp);
    p = swz64<IMM>(b0); XK(b0, p, kp);
}

#define DPP_X1 0xB1   // quad_perm [1,0,3,2]
#define DPP_X2 0x4E   // quad_perm [2,3,0,1]
#define DPP_X7 0x141  // row_half_mirror
#define DPP_X15 0x140 // row_mirror
#define SWZ_X4  0x101F // BitMode xor=4, and=0x1F
#define SWZ_X23 0x5C1F // BitMode xor=23, and=0x1F

__global__ __launch_bounds__(256) void select_topk(
    const float* __restrict__ S, int* __restrict__ Eo, float* __restrict__ Po)
{
    const int lane = threadIdx.x & 63;
    const int pair = blockIdx.x * 4 + (threadIdx.x >> 6);
    const float* s1 = S + (size_t)pair * 256;
    const float* s2 = s1 + 128;

    u64 a0 = pack_key(s1[lane], lane);
    u64 a1 = pack_key(s1[lane + 64], lane + 64);
    u64 b0 = pack_key(s2[lane], lane);
    u64 b1 = pack_key(s2[lane + 64], lane + 64);

    // Phase A: sort every 8-lane block descending (6 stages)
    cx4d<DPP_X1>(a0, a1, b0, b1, ((lane & 1) == 0) == ((lane & 2) == 0));
    cx4d<DPP_X2>(a0, a1, b0, b1, ((lane & 2) == 0) == ((lane & 4) == 0));
    cx4d<DPP_X1>(a0, a1, b0, b1, ((lane & 1) == 0) == ((lane & 4) == 0));
    cx4s<SWZ_X4>(a0, a1, b0, b1, (lane & 4) == 0);
    cx4d<DPP_X2>(a0, a1, b0, b1, (lane & 2) == 0);
    cx4d<DPP_X1>(a0, a1, b0, b1, (lane & 1) == 0);
    // Level 1: merge-prune 8|8 within 16-lane groups (reversal pairing ^15)
    cx4d<DPP_X15>(a0, a1, b0, b1, (lane & 8) == 0);
    cx4s<SWZ_X4>(a0, a1, b0, b1, (lane & 4) == 0);
    cx4d<DPP_X2>(a0, a1, b0, b1, (lane & 2) == 0);
    cx4d<DPP_X1>(a0, a1, b0, b1, (lane & 1) == 0);
    // Level 2: merge lists 16 lanes apart (^23)
    cx4s<SWZ_X23>(a0, a1, b0, b1, (lane & 16) == 0);
    cx4s<SWZ_X4>(a0, a1, b0, b1, (lane & 4) == 0);
    cx4d<DPP_X2>(a0, a1, b0, b1, (lane & 2) == 0);
    cx4d<DPP_X1>(a0, a1, b0, b1, (lane & 1) == 0);
    // Level 3: merge lists 32 lanes apart (^39; crosses 32-lane -> bpermute)
    cx4b(a0, a1, b0, b1, 39, (lane & 32) == 0);
    cx4s<SWZ_X4>(a0, a1, b0, b1, (lane & 4) == 0);
    cx4d<DPP_X2>(a0, a1, b0, b1, (lane & 2) == 0);
    cx4d<DPP_X1>(a0, a1, b0, b1, (lane & 1) == 0);
    // Level C: cross-reg merge (reg1 reversed via ^7), clean on reg0
    {
        u64 p = dpp64<DPP_X7>(a1);
        if (p > a0) a0 = p;
        p = dpp64<DPP_X7>(b1);
        if (p > b0) b0 = p;
    }
    cx2s<SWZ_X4>(a0, b0, (lane & 4) == 0);
    cx2d<DPP_X2>(a0, b0, (lane & 2) == 0);
    cx2d<DPP_X1>(a0, b0, (lane & 1) == 0);
    // now rank-i of s1 at lane i (key a0), same for s2 (key b0), i in [0,8)

    // ---- combo top-8 via dominance pruning: (i+1)*(j+1) <= 8 -> 20 pairs ----
    const int p = lane;
    int ci, cj;
    if (p < 8)       { ci = 0; cj = p; }
    else if (p < 16) { ci = (0x33221111u >> ((p - 8) * 4)) & 15;
                       cj = (0x10103210u >> ((p - 8) * 4)) & 15; }
    else             { ci = p - 12; cj = 0; }

    const u64 k1c = sg64(a0, ci);
    const u64 k2c = sg64(b0, cj);
    const float sum = (p < 20) ? (key_val(k1c) + key_val(k2c)) : -INFINITY;
    const int   c   = ci * 16 + cj;   // flat combo index (tie-break key)

    int rank = 0; float m = -INFINITY;
#pragma unroll
    for (int q = 0; q < 20; ++q) {
        const float sq = __shfl(sum, q);
        const int   cq = __shfl(c, q);
        if (sq > sum || (sq == sum && cq < c)) ++rank;
        m = fmaxf(m, sq);
    }

    float ex = (p < 20 && rank < 8) ? expf(sum - m) : 0.f;
    float esum = ex;
#pragma unroll
    for (int off = 1; off < 64; off <<= 1) esum += __shfl_xor(esum, off);

    if (p < 20 && rank < 8) {
        Eo[pair * 8 + rank] = key_idx(k1c) * NSUB + key_idx(k2c);
        Po[pair * 8 + rank] = ex / esum;
    }
}

// ---------------------------------------------------------------------------
// MoE apply v2: all 8 expert-row gathers issued upfront (8x MLP), DPP-only
// wave sum (row_shr 1,2,4,8 + row_bcast 15,31 -> lane 63 -> readlane).
// ---------------------------------------------------------------------------
__device__ __forceinline__ float wave_sum_dpp(float x) {
    float t;
    t = __uint_as_float((unsigned)__builtin_amdgcn_update_dpp(
        0, (int)__float_as_uint(x), 0x111, 0xF, 0xF, true)); x += t; // row_shr:1
    t = __uint_as_float((unsigned)__builtin_amdgcn_update_dpp(
        0, (int)__float_as_uint(x), 0x112, 0xF, 0xF, true)); x += t; // row_shr:2
    t = __uint_as_float((unsigned)__builtin_amdgcn_update_dpp(
        0, (int)__float_as_uint(x), 0x114, 0xF, 0xF, true)); x += t; // row_shr:4
    t = __uint_as_float((unsigned)__builtin_amdgcn_update_dpp(
        0, (int)__float_as_uint(x), 0x118, 0xF, 0xF, true)); x += t; // row_shr:8
    t = __uint_as_float((unsigned)__builtin_amdgcn_update_dpp(
        0, (int)__float_as_uint(x), 0x142, 0xF, 0xF, true)); x += t; // row_bcast:15
    t = __uint_as_float((unsigned)__builtin_amdgcn_update_dpp(
        0, (int)__float_as_uint(x), 0x143, 0xF, 0xF, true)); x += t; // row_bcast:31
    return __uint_as_float((unsigned)__builtin_amdgcn_readlane(
        (int)__float_as_uint(x), 63));
}

__global__ __launch_bounds__(256) void moe_apply(
    const unsigned short* __restrict__ Hall, const float* __restrict__ xproj,
    const int* __restrict__ E, const float* __restrict__ P,
    unsigned short* __restrict__ accb)
{
    const int n = blockIdx.x, t = threadIdx.x, w = t >> 6, lane = t & 63;
    __shared__ float wacc[4][512];

    float xr[8];
    *(float4*)&xr[0] = *(const float4*)&xproj[(size_t)n * 512 + lane * 8];
    *(float4*)&xr[4] = *(const float4*)&xproj[(size_t)n * 512 + lane * 8 + 4];

    const int* Ep = E + ((size_t)n * 4 + w) * 8;
    const float* Pp = P + ((size_t)n * 4 + w) * 8;

    // wave-uniform expert ids -> SGPR; issue all 8 gathers before any compute
    int e[8]; float pp[8];
#pragma unroll
    for (int k = 0; k < 8; ++k) {
        e[k] = __builtin_amdgcn_readfirstlane(Ep[k]);
        pp[k] = Pp[k];
    }
    bf16x8 hv[8];
#pragma unroll
    for (int k = 0; k < 8; ++k)
        hv[k] = *(const bf16x8*)&Hall[(size_t)e[k] * 512 + lane * 8];

    float ar[8] = {};
#pragma unroll
    for (int k = 0; k < 8; ++k) {
        float h[8];
#pragma unroll
        for (int j = 0; j < 8; ++j) h[j] = b2f((unsigned short)hv[k][j]);
        float d = 0.f;
#pragma unroll
        for (int j = 0; j < 8; ++j) d = fmaf(h[j], xr[j], d);
        d = wave_sum_dpp(d);
        const float act = gelu_exact(d) * pp[k];
#pragma unroll
        for (int j = 0; j < 8; ++j) ar[j] = fmaf(act, h[j], ar[j]);
    }
    *(float4*)&wacc[w][lane * 8] = *(float4*)&ar[0];
    *(float4*)&wacc[w][lane * 8 + 4] = *(float4*)&ar[4];
    __syncthreads();

    const float r0 = wacc[0][t] + wacc[1][t] + wacc[2][t] + wacc[3][t];
    const float r1 = wacc[0][t + 256] + wacc[1][t + 256] + wacc[2][t + 256] + wacc[3][t + 256];
    accb[(size_t)n * 512 + t] = f2b(r0);
    accb[(size_t)n * 512 + 256 + t] = f2b(r1);
}

// ---------------------------------------------------------------------------
extern "C" void kernel_launch(void* const* d_in, const int* in_sizes, int n_in,
                              void* d_out, int out_size, void* d_ws, size_t ws_size,
                              hipStream_t stream)
{
    const float* x       = (const float*)d_in[0];
    const float* Wq      = (const float*)d_in[1];
    const float* bq      = (const float*)d_in[2];
    const float* gamma   = (const float*)d_in[3];
    const float* beta    = (const float*)d_in[4];
    const float* sk1     = (const float*)d_in[5];
    const float* sk2     = (const float*)d_in[6];
    const float* latents = (const float*)d_in[7];
    const float* W1      = (const float*)d_in[8];
    const float* W2      = (const float*)d_in[9];
    float* out = (float*)d_out;
    float* ws  = (float*)d_ws;

    // workspace layout (float offsets), peak 22087680 floats = 88.35 MB.
    // Stream-order-safe aliases (write-before-read checked per launch order):
    //   q [0,8.4M) ............ written s1, read s2/s3; -> Hall bf16 (s5+)
    //   xh [8.4M,12.6M) ........ written s0, read s1,s6; -> S (s3)
    //   xl [12.6M,16.8M) ....... written s0, read s1; -> ps/pq (s2) -> S (s3)
    //   S  [8.4M,16.8M) ........ written s3, read s4; -> accb (s7), latb (after s4)
    //   Wqh/Wql in xproj region: read s1; xproj written s6 (after s1)
    float*          q     = ws;
    unsigned short* Hall  = (unsigned short*)ws;
    unsigned short* xh    = (unsigned short*)(ws + 8388608);
    unsigned short* xl    = (unsigned short*)(ws + 12582912);
    float*          S     = ws + 8388608;
    unsigned short* accb  = (unsigned short*)(ws + 8388608);
    float*          ps    = ws + 12582912;
    float*          pq    = ws + 12845056;
    unsigned short* latb  = (unsigned short*)(ws + 10485760);
    float*          xproj = ws + 16777216;
    unsigned short* Wqh   = (unsigned short*)(ws + 16777216);
    unsigned short* Wql   = (unsigned short*)(ws + 17301504);
    unsigned short* W2a   = (unsigned short*)(ws + 20971520);
    unsigned short* W1t   = (unsigned short*)(ws + 21233664);
    unsigned short* Wvt   = (unsigned short*)(ws + 21299200);
    float*          scale = ws + 21561344;
    float*          shift = ws + 21562368;
    int*            E     = (int*)(ws + 21563392);
    float*          P     = ws + 21825536;

    // 0. merged casts/splits (latents cast deferred until S region is dead)
    prep_all<<<12288, 256, 0, stream>>>(x, Wq, W2, W1,
                                        xh, xl, Wqh, Wql, W2a, W1t, Wvt);

    // 1. q = x @ Wq^T + bq   (split-precision MFMA, fp32-class accuracy)
    mfma_nt<1, 1><<<dim3(64, 8), 256, 0, stream>>>(
        xh, xl, Wqh, Wql, 1024, q, nullptr, 1024, bq);

    // 2. batchnorm stats
    col_stats_partial<<<256, 256, 0, stream>>>(q, ps, pq);
    col_stats_final<<<4, 256, 0, stream>>>(ps, pq, gamma, beta, scale, shift);

    // 6. x_proj = x @ W2[:, :1024]^T  (bf16 MFMA; before S overwrites xh;
    //    destroys Wqh/Wql which are now dead)
    mfma_nt<0, 0><<<dim3(64, 4), 256, 0, stream>>>(
        xh, nullptr, W2a, nullptr, 1024, xproj, nullptr, 512, nullptr);

    // 3. S = (q*scale+shift) @ sk^T   (fp32 for selection exactness)
    gemm_shead<<<dim3(64, 8), 256, 0, stream>>>(
        q, 1024, sk1, sk2, 128, S, 1024, 128, scale, shift);

    // 4. top-k selection (DPP/swizzle bitonic + dominance-pruned combos)
    select_topk<<<8192, 256, 0, stream>>>(S, E, P);

    // 0b. latents cast (into dead S region)
    cast_rows<<<4096, 256, 0, stream>>>(latents, 256, latb, 16384, 256);

    // 5. H_all = gelu(latents @ W1) -> bf16   [overwrites q]
    mfma_nt<2, 0><<<dim3(128, 4), 256, 0, stream>>>(
        latb, nullptr, W1t, nullptr, 256, nullptr, Hall, 512, nullptr);

    // 7. gather + gate + weighted accumulate -> accb bf16  [overwrites S head]
    moe_apply<<<8192, 256, 0, stream>>>(Hall, xproj, E, P, accb);

    // 8. out = acc @ Wv / 4
    mfma_nt<3, 0><<<dim3(64, 8), 256, 0, stream>>>(
        accb, nullptr, Wvt, nullptr, 512, out, nullptr, 1024, nullptr);
}